// Round 12
// baseline (695.569 us; speedup 1.0000x reference)
//
#include <hip/hip_runtime.h>
#include <cstdint>
#include <cstddef>

// Problem shape (fixed by the reference): B=8, C=192, Tx=512, Ty=2048.
#define BB 8
#define CC 192
#define TXX 512
#define TYY 2048

#define NEG_INF (-1e9f)
#define HALF_LOG_2PI 0.9189385332046727f  // 0.5*log(2*pi)

// ---- output layout (floats, concatenated in return order) ----
#define O1 8388608
#define O2 11534336
#define O3 14680064
#define O4 14680065

// ---- workspace layout (bytes) ----
#define WS_NEG   0           // neg_cent fp32 [B,Ty,Tx]           33,554,432 B
#define WS_S     33554432    // s_p_sq_r [B,C,Tx]                  3,145,728 B
#define WS_MSR   36700160    // m_p * s  [B,C,Tx]                  3,145,728 B
#define WS_BIAS  39845888    // nc1+nc4  [B,Tx]                       16,384 B
#define WS_DIRS  39862272    // dir bits [B,Ty/4,64] dwords        1,048,576 B
#define WS_IDX   40910848    // idx_map  [B,Ty] int                   65,536 B
#define WS_LENS  40976384    // int text_len[8], spec_len[8]             64 B
#define WS_PART  40976448    // kl partials [3072] float              12,288 B

// ---------------------------------------------------------------------------
__global__ void k_zero(float* __restrict__ out) {
    int64_t i = (int64_t)blockIdx.x * blockDim.x + threadIdx.x;
    const int64_t n4 = (int64_t)BB * TYY * TXX / 4;
    float4 z4 = make_float4(0.f, 0.f, 0.f, 0.f);
    float4* p4 = (float4*)out;
    for (int64_t k = i; k < n4; k += (int64_t)gridDim.x * blockDim.x) p4[k] = z4;
    if (i < BB * TXX) out[O4 + i] = 0.0f;
}

__global__ void k_prep(const float* __restrict__ logs_p, const float* __restrict__ m_p,
                       float* __restrict__ s, float* __restrict__ msr) {
    int i = blockIdx.x * blockDim.x + threadIdx.x;
    float lp = logs_p[i], m = m_p[i];
    float sv = expf(-2.0f * lp);
    s[i] = sv;
    msr[i] = m * sv;
}

__global__ void k_bias(const float* __restrict__ logs_p, const float* __restrict__ m_p,
                       const float* __restrict__ msr, float* __restrict__ bias) {
    int i = blockIdx.x * blockDim.x + threadIdx.x;  // B*Tx = 4096 threads
    int b = i >> 9, x = i & (TXX - 1);
    size_t base = (size_t)b * CC * TXX + x;
    const float* lpb = logs_p + base;
    const float* mb  = m_p + base;
    const float* msb = msr + base;
    float acc = 0.f;
#pragma unroll 8
    for (int c = 0; c < CC; ++c)
        acc += -HALF_LOG_2PI - lpb[(size_t)c * TXX] - 0.5f * mb[(size_t)c * TXX] * msb[(size_t)c * TXX];
    bias[i] = acc;
}

__global__ void k_len(const float* __restrict__ tmask, const float* __restrict__ smask,
                      int* __restrict__ lens) {
    __shared__ float red[256];
    int b = blockIdx.x, tid = threadIdx.x;
    float ts = 0.f;
    for (int i = tid; i < TXX; i += 256) ts += tmask[b * TXX + i];
    red[tid] = ts; __syncthreads();
    for (int s = 128; s > 0; s >>= 1) { if (tid < s) red[tid] += red[tid + s]; __syncthreads(); }
    if (tid == 0) lens[b] = (int)(red[0] + 0.5f);
    __syncthreads();
    float ss = 0.f;
    for (int i = tid; i < TYY; i += 256) ss += smask[b * TYY + i];
    red[tid] = ss; __syncthreads();
    for (int s = 128; s > 0; s >>= 1) { if (tid < s) red[tid] += red[tid + s]; __syncthreads(); }
    if (tid == 0) lens[8 + b] = (int)(red[0] + 0.5f);
}

// neg_cent GEMM v2. R11 post-mortem: the 64x64/4x4 tile ran ~24 TF (15% of
// the 157 TF fp32 roofline) because it was LDS-throughput bound (12.3 KB
// LDS traffic per block-k-step = 96 cyc vs 64 cyc FMA issue) and paid 24
// __syncthreads across 2048 small blocks. R12: 128x128 tile, 8x8 per
// thread, BK=8 -> 24 floats LDS per 128 FLOP per thread (~240 cyc LDS vs
// 256 cyc FMA per block-k-step, compute-bound), 512 blocks = 2/CU.
// K-accumulation order (ascending c, fma(z,m)+fma(a2,s) chain) identical
// to v1 -> bit-identical outputs.
__global__ __launch_bounds__(256) void k_gemm(const float* __restrict__ z,
                                              const float* __restrict__ msr,
                                              const float* __restrict__ sarr,
                                              const float* __restrict__ bias,
                                              float* __restrict__ neg) {
    __shared__ float Zs[8][132], Ms[8][132], Ss[8][132];  // +4 pad
    int tid = threadIdx.x;
    int tx = tid & 15, ty = tid >> 4;          // 16x16 threads; 8 cols/8 rows each
    int x0 = blockIdx.x * 128, t0 = blockIdx.y * 128, b = blockIdx.z;
    const float* zb = z    + (size_t)b * CC * TYY;
    const float* mb = msr  + (size_t)b * CC * TXX;
    const float* sb = sarr + (size_t)b * CC * TXX;
    int lr = tid >> 5, lc = (tid & 31) * 4;    // staging: k-row, col*4
    float acc[8][8] = {};
    for (int k0 = 0; k0 < CC; k0 += 8) {
        float4 zv = *(const float4*)(zb + (size_t)(k0 + lr) * TYY + t0 + lc);
        float4 mv = *(const float4*)(mb + (size_t)(k0 + lr) * TXX + x0 + lc);
        float4 sv = *(const float4*)(sb + (size_t)(k0 + lr) * TXX + x0 + lc);
        __syncthreads();
        *(float4*)&Zs[lr][lc] = zv;
        *(float4*)&Ms[lr][lc] = mv;
        *(float4*)&Ss[lr][lc] = sv;
        __syncthreads();
#pragma unroll
        for (int k = 0; k < 8; ++k) {
            float4 a0 = *(const float4*)&Zs[k][ty * 8];
            float4 a1 = *(const float4*)&Zs[k][ty * 8 + 4];
            float4 m0 = *(const float4*)&Ms[k][tx * 8];
            float4 m1 = *(const float4*)&Ms[k][tx * 8 + 4];
            float4 q0 = *(const float4*)&Ss[k][tx * 8];
            float4 q1 = *(const float4*)&Ss[k][tx * 8 + 4];
            float av[8]  = {a0.x, a0.y, a0.z, a0.w, a1.x, a1.y, a1.z, a1.w};
            float bmv[8] = {m0.x, m0.y, m0.z, m0.w, m1.x, m1.y, m1.z, m1.w};
            float bsv[8] = {q0.x, q0.y, q0.z, q0.w, q1.x, q1.y, q1.z, q1.w};
#pragma unroll
            for (int i2 = 0; i2 < 8; ++i2) {
                float a2 = -0.5f * av[i2] * av[i2];
#pragma unroll
                for (int j = 0; j < 8; ++j)
                    acc[i2][j] += av[i2] * bmv[j] + a2 * bsv[j];
            }
        }
    }
    float4 b0 = *(const float4*)(bias + b * TXX + x0 + tx * 8);
    float4 b1 = *(const float4*)(bias + b * TXX + x0 + tx * 8 + 4);
    float bv[8] = {b0.x, b0.y, b0.z, b0.w, b1.x, b1.y, b1.z, b1.w};
#pragma unroll
    for (int i2 = 0; i2 < 8; ++i2) {
        int t = t0 + ty * 8 + i2;
        float* orow = neg + ((size_t)b * TYY + t) * TXX + x0 + tx * 8;
        float4 o0, o1;
        o0.x = acc[i2][0] + bv[0]; o0.y = acc[i2][1] + bv[1];
        o0.z = acc[i2][2] + bv[2]; o0.w = acc[i2][3] + bv[3];
        o1.x = acc[i2][4] + bv[4]; o1.y = acc[i2][5] + bv[5];
        o1.z = acc[i2][6] + bv[6]; o1.w = acc[i2][7] + bv[7];
        *(float4*)orow = o0;
        *(float4*)(orow + 4) = o1;
    }
}

// MAS forward pass (R11 structure, unchanged): two DP waves (A: x<256,
// B: x>=256, B one group behind consuming A's boundary v[255] via LDS ring)
// + 4 feeder waves staging 8-row groups into a 4-slot LDS ring.
__global__ __launch_bounds__(384, 1) void k_fwd(const float* __restrict__ neg,
                                                const int* __restrict__ lens,
                                                uint32_t* __restrict__ dirs) {
    __shared__ __align__(16) float ring[4 * 4096];  // 4 slots x 8 rows x 512 f
    __shared__ float bnd[32];                       // A's v[255] ring
    __shared__ int feed_done[4];
    __shared__ int consB_cnt;
    __shared__ int bnd_cnt;

    int b = blockIdx.x, tid = threadIdx.x;
    int wave = tid >> 6, lane = tid & 63;
    const float* nc = neg + (size_t)b * TYY * TXX;
    uint32_t* db32 = dirs + (size_t)b * (TYY / 4) * 64;

    if (tid == 0) {
        feed_done[0] = feed_done[1] = feed_done[2] = feed_done[3] = 0;
        consB_cnt = 0; bnd_cnt = 0;
    }
    __syncthreads();

    if (wave >= 2) {
        // ---- feeders: wave w stages groups g == w-2 (mod 4) ----
        int w = wave - 2;
        const float4* nc4 = (const float4*)nc;
        int cnt = 0;
        for (int g = w; g < TYY / 8; g += 4) {
            while (*(volatile int*)&consB_cnt < g - 3) __builtin_amdgcn_s_sleep(1);
            asm volatile("" ::: "memory");
            const float4* g4 = nc4 + (size_t)g * 1024;  // 8 rows x 128 float4
            float4 t[16];
#pragma unroll
            for (int r = 0; r < 8; ++r) {
                t[2 * r]     = g4[r * 128 + lane];
                t[2 * r + 1] = g4[r * 128 + 64 + lane];
            }
            float4* lb = (float4*)(ring + (size_t)(g & 3) * 4096);
#pragma unroll
            for (int r = 0; r < 8; ++r) {
                lb[r * 128 + lane]      = t[2 * r];
                lb[r * 128 + 64 + lane] = t[2 * r + 1];
            }
            asm volatile("" ::: "memory");       // DS in-order per wave
            ++cnt;
            if (lane == 0) *(volatile int*)&feed_done[w] = cnt;
        }
        return;
    }

    // ---- DP waves: wave 0 = A (x 0..255), wave 1 = B (x 256..511) ----
    bool isA = (wave == 0);
    int xbase = isA ? 0 : 256;
    float v[4];
#pragma unroll
    for (int j = 0; j < 4; ++j) v[j] = NEG_INF;
    uint32_t acc = 0;

    for (int g = 0; g < TYY / 8; ++g) {
        int f = g & 3, need = (g >> 2) + 1;
        while (*(volatile int*)&feed_done[f] < need) {}
        if (isA) {
            while (*(volatile int*)&consB_cnt < g - 2) {}
        } else {
            while (*(volatile int*)&bnd_cnt < 8 * g + 7) {}
        }
        asm volatile("" ::: "memory");

        float bn[8];
        if (!isA) {
#pragma unroll
            for (int k = 0; k < 8; ++k) bn[k] = bnd[(8 * g - 1 + k) & 31];
        }
        const float4* lb = (const float4*)(ring + (size_t)(g & 3) * 4096)
                           + (isA ? 0 : 64) + lane;
        float4 c_cur = lb[0], c_nxt = lb[128];
#pragma unroll
        for (int r = 0; r < 8; ++r) {
            float4 cpf;
            if (r < 6) cpf = lb[(r + 2) * 128];
            int y = 8 * g + r;
            unsigned d = 0;
            if (y == 0) {
                if (isA && lane == 0) v[0] = c_cur.x;  // row 0: only x==0 scored
            } else {
                float sc[4] = {c_cur.x, c_cur.y, c_cur.z, c_cur.w};
                float pl = __int_as_float(__builtin_amdgcn_update_dpp(
                    0, __float_as_int(v[3]), 0x138, 0xF, 0xF, false));
                if (lane == 0) pl = isA ? NEG_INF : bn[r];
                float nv[4];
#pragma unroll
                for (int jj = 0; jj < 4; ++jj) {
                    float diag = (jj == 0) ? pl : v[jj - 1];
                    if (diag > v[jj]) d |= (1u << jj);
                    nv[jj] = sc[jj] + fmaxf(v[jj], diag);
                }
#pragma unroll
                for (int jj = 0; jj < 4; ++jj) v[jj] = nv[jj];
            }
            unsigned t_ = (unsigned)(y - (xbase + 4 * lane));
            if (t_ < 4u) d |= (1u << t_);            // fold x==y
            unsigned dl = (unsigned)__builtin_amdgcn_update_dpp(
                0, (int)d, 0x138, 0xF, 0xF, false);
            unsigned byteval = (d << 4) | dl;
            acc |= byteval << ((r & 3) * 8);
            if ((r & 3) == 3) {
                if (lane & 1)
                    db32[(y >> 2) * 64 + (isA ? 0 : 32) + (lane >> 1)] = acc;
                acc = 0;
            }
            if (isA && lane == 63) bnd[y & 31] = v[3];
            c_cur = c_nxt; c_nxt = cpf;
        }
        asm volatile("" ::: "memory");
        if (isA) { if (lane == 0) *(volatile int*)&bnd_cnt = 8 * g + 8; }
        else     { if (lane == 0) *(volatile int*)&consB_cnt = g + 1; }
    }
}

// MAS backtrack: 32-row slabs; lane j holds a 64-bit window of row y0-j's
// bits; move = (idx!=0) & bit (x==y folded in fwd).
__global__ __launch_bounds__(64, 1) void k_bwd(const int* __restrict__ lens,
                                               const uint32_t* __restrict__ dirs,
                                               int* __restrict__ idx_map) {
    int b = blockIdx.x, lane = threadIdx.x;
    const uint32_t* db32 = dirs + (size_t)b * (TYY / 4) * 64;
    int tlen = lens[b], slen = lens[8 + b];

    int idx = tlen - 1;
    int y0 = slen - 1;
    while (y0 >= 0) {
        int nsteps = (y0 + 1 < 32) ? y0 + 1 : 32;
        int y = y0 - lane;
        int yy = (y < 0) ? 0 : y;
        int w0 = (idx >> 5) - 1;
        if (w0 < 0) w0 = 0;
        if (w0 > 14) w0 = 14;
        int qrow = (yy >> 2) * 64;
        int byteoff = (yy & 3) * 8;
        uint32_t lo = 0, hi = 0;
        if (lane < 32) {
#pragma unroll
            for (int k = 0; k < 4; ++k)
                lo |= ((db32[qrow + 4 * w0 + k] >> byteoff) & 0xffu) << (8 * k);
#pragma unroll
            for (int k = 0; k < 4; ++k)
                hi |= ((db32[qrow + 4 * w0 + 4 + k] >> byteoff) & 0xffu) << (8 * k);
        }
        int base = w0 << 5;
        int cap = 0;
#pragma unroll
        for (int j = 0; j < 32; ++j) {
            if (lane == j) cap = idx;
            uint32_t l = (uint32_t)__builtin_amdgcn_readlane((int)lo, j);
            uint32_t h = (uint32_t)__builtin_amdgcn_readlane((int)hi, j);
            int bp = idx - base;              // 0..63
            uint32_t word = (bp & 32) ? h : l;
            int bit = (int)((word >> (bp & 31)) & 1u);
            int move = (int)(idx != 0) & bit;
            idx -= move;
        }
        if (lane < nsteps) idx_map[b * TYY + (y0 - lane)] = cap;
        y0 -= 32;
    }
}

// Scatter path one-hots + duration histogram from idx_map.
__global__ void k_scatter(const int* __restrict__ lens, const int* __restrict__ idx_map,
                          float* __restrict__ out) {
    int i = blockIdx.x * blockDim.x + threadIdx.x;  // B*Ty threads
    int b = i >> 11, y = i & (TYY - 1);
    if (y < lens[8 + b]) {
        int x = idx_map[i];
        out[(size_t)i * TXX + x] = 1.0f;
        atomicAdd(&out[O4 + b * TXX + x], 1.0f);
    }
}

// Gather m_p/logs_p onto spec frames via idx_map; fused KL partial sums.
__global__ __launch_bounds__(256) void k_gather(const float* __restrict__ z_p,
                                                const float* __restrict__ m_p,
                                                const float* __restrict__ logs_p,
                                                const float* __restrict__ logs_q,
                                                const int* __restrict__ lens,
                                                const int* __restrict__ idx_map,
                                                float* __restrict__ out,
                                                float* __restrict__ partials) {
    const int S = BB * CC * TYY / 4;
    int base = blockIdx.x * 256 + threadIdx.x;
    float klsum = 0.f;
#pragma unroll
    for (int r = 0; r < 4; ++r) {
        int i = base + r * S;
        int t = i & (TYY - 1);
        int bc = i >> 11;
        int b = bc / CC;
        float ma = 0.f, la = 0.f;
        if (t < lens[8 + b]) {
            int x = idx_map[b * TYY + t];
            size_t off = (size_t)bc * TXX + x;
            ma = m_p[off];
            la = logs_p[off];
            float zv = z_p[i], lq = logs_q[i];
            float dz = zv - ma;
            klsum += la - lq - 0.5f + 0.5f * dz * dz * expf(-2.0f * la);
        }
        out[O1 + i] = ma;
        out[O2 + i] = la;
    }
    for (int o = 32; o > 0; o >>= 1) klsum += __shfl_down(klsum, o);
    __shared__ float red[4];
    if ((threadIdx.x & 63) == 0) red[threadIdx.x >> 6] = klsum;
    __syncthreads();
    if (threadIdx.x == 0) partials[blockIdx.x] = red[0] + red[1] + red[2] + red[3];
}

__global__ void k_final(const float* __restrict__ partials, const int* __restrict__ lens,
                        float* __restrict__ out) {
    float s = 0.f;
    for (int i = threadIdx.x; i < 3072; i += 256) s += partials[i];
    for (int o = 32; o > 0; o >>= 1) s += __shfl_down(s, o);
    __shared__ float red[4];
    if ((threadIdx.x & 63) == 0) red[threadIdx.x >> 6] = s;
    __syncthreads();
    if (threadIdx.x == 0) {
        float tot = 0.f;
        for (int b = 0; b < 8; ++b) tot += (float)lens[8 + b];
        out[O3] = (red[0] + red[1] + red[2] + red[3]) / tot;
    }
}

extern "C" void kernel_launch(void* const* d_in, const int* in_sizes, int n_in,
                              void* d_out, int out_size, void* d_ws, size_t ws_size,
                              hipStream_t stream) {
    const float* z_p    = (const float*)d_in[0];
    const float* m_p    = (const float*)d_in[1];
    const float* logs_p = (const float*)d_in[2];
    const float* logs_q = (const float*)d_in[3];
    const float* tmask  = (const float*)d_in[4];
    const float* smask  = (const float*)d_in[5];
    float* out = (float*)d_out;
    char* ws = (char*)d_ws;

    float*    neg      = (float*)(ws + WS_NEG);
    float*    sarr     = (float*)(ws + WS_S);
    float*    msr      = (float*)(ws + WS_MSR);
    float*    bias     = (float*)(ws + WS_BIAS);
    uint32_t* dirs     = (uint32_t*)(ws + WS_DIRS);
    int*      idx_map  = (int*)(ws + WS_IDX);
    int*      lens     = (int*)(ws + WS_LENS);
    float*    partials = (float*)(ws + WS_PART);

    hipLaunchKernelGGL(k_zero,    dim3(2048),      dim3(256), 0, stream, out);
    hipLaunchKernelGGL(k_prep,    dim3(3072),      dim3(256), 0, stream, logs_p, m_p, sarr, msr);
    hipLaunchKernelGGL(k_bias,    dim3(16),        dim3(256), 0, stream, logs_p, m_p, msr, bias);
    hipLaunchKernelGGL(k_len,     dim3(8),         dim3(256), 0, stream, tmask, smask, lens);
    hipLaunchKernelGGL(k_gemm,    dim3(4, 16, 8),  dim3(256), 0, stream, z_p, msr, sarr, bias, neg);
    hipLaunchKernelGGL(k_fwd,     dim3(8),         dim3(384), 0, stream, neg, lens, dirs);
    hipLaunchKernelGGL(k_bwd,     dim3(8),         dim3(64),  0, stream, lens, dirs, idx_map);
    hipLaunchKernelGGL(k_scatter, dim3(64),        dim3(256), 0, stream, lens, idx_map, out);
    hipLaunchKernelGGL(k_gather,  dim3(3072),      dim3(256), 0, stream, z_p, m_p, logs_p, logs_q,
                       lens, idx_map, out, partials);
    hipLaunchKernelGGL(k_final,   dim3(1),         dim3(256), 0, stream, partials, lens, out);
}

// Round 13
// 674.026 us; speedup vs baseline: 1.0320x; 1.0320x over previous
//
#include <hip/hip_runtime.h>
#include <cstdint>
#include <cstddef>

// Problem shape (fixed by the reference): B=8, C=192, Tx=512, Ty=2048.
#define BB 8
#define CC 192
#define TXX 512
#define TYY 2048
#define NG (TYY / 8)   // 256 groups of 8 rows

#define NEG_INF (-1e9f)
#define HALF_LOG_2PI 0.9189385332046727f  // 0.5*log(2*pi)

// ---- output layout (floats, concatenated in return order) ----
#define O1 8388608
#define O2 11534336
#define O3 14680064
#define O4 14680065

// ---- workspace layout (bytes) ----
#define WS_NEG   0           // neg_cent fp32 [B,Ty,Tx]           33,554,432 B
#define WS_S     33554432    // s_p_sq_r [B,C,Tx]                  3,145,728 B
#define WS_MSR   36700160    // m_p * s  [B,C,Tx]                  3,145,728 B
#define WS_BIAS  39845888    // nc1+nc4  [B,Tx]                       16,384 B
#define WS_DIRS  39862272    // dir bits [B,Ty/4,64] dwords        1,048,576 B
#define WS_IDX   40910848    // idx_map  [B,Ty] int                   65,536 B
#define WS_LENS  40976384    // int text_len[8], spec_len[8]             64 B
#define WS_PART  40976448    // kl partials [3072] float              12,288 B

// ---------------------------------------------------------------------------
__global__ void k_zero(float* __restrict__ out) {
    int64_t i = (int64_t)blockIdx.x * blockDim.x + threadIdx.x;
    const int64_t n4 = (int64_t)BB * TYY * TXX / 4;
    float4 z4 = make_float4(0.f, 0.f, 0.f, 0.f);
    float4* p4 = (float4*)out;
    for (int64_t k = i; k < n4; k += (int64_t)gridDim.x * blockDim.x) p4[k] = z4;
    if (i < BB * TXX) out[O4 + i] = 0.0f;
}

__global__ void k_prep(const float* __restrict__ logs_p, const float* __restrict__ m_p,
                       float* __restrict__ s, float* __restrict__ msr) {
    int i = blockIdx.x * blockDim.x + threadIdx.x;
    float lp = logs_p[i], m = m_p[i];
    float sv = expf(-2.0f * lp);
    s[i] = sv;
    msr[i] = m * sv;
}

__global__ void k_bias(const float* __restrict__ logs_p, const float* __restrict__ m_p,
                       const float* __restrict__ msr, float* __restrict__ bias) {
    int i = blockIdx.x * blockDim.x + threadIdx.x;  // B*Tx = 4096 threads
    int b = i >> 9, x = i & (TXX - 1);
    size_t base = (size_t)b * CC * TXX + x;
    const float* lpb = logs_p + base;
    const float* mb  = m_p + base;
    const float* msb = msr + base;
    float acc = 0.f;
#pragma unroll 8
    for (int c = 0; c < CC; ++c)
        acc += -HALF_LOG_2PI - lpb[(size_t)c * TXX] - 0.5f * mb[(size_t)c * TXX] * msb[(size_t)c * TXX];
    bias[i] = acc;
}

__global__ void k_len(const float* __restrict__ tmask, const float* __restrict__ smask,
                      int* __restrict__ lens) {
    __shared__ float red[256];
    int b = blockIdx.x, tid = threadIdx.x;
    float ts = 0.f;
    for (int i = tid; i < TXX; i += 256) ts += tmask[b * TXX + i];
    red[tid] = ts; __syncthreads();
    for (int s = 128; s > 0; s >>= 1) { if (tid < s) red[tid] += red[tid + s]; __syncthreads(); }
    if (tid == 0) lens[b] = (int)(red[0] + 0.5f);
    __syncthreads();
    float ss = 0.f;
    for (int i = tid; i < TYY; i += 256) ss += smask[b * TYY + i];
    red[tid] = ss; __syncthreads();
    for (int s = 128; s > 0; s >>= 1) { if (tid < s) red[tid] += red[tid + s]; __syncthreads(); }
    if (tid == 0) lens[8 + b] = (int)(red[0] + 0.5f);
}

// neg_cent GEMM (R11 v1 — 64x64 tile, BK=16, 8 blocks/CU; reverted from the
// R12 128x128 variant which lost ~25 us at 2 blocks/CU).
__global__ __launch_bounds__(256) void k_gemm(const float* __restrict__ z,
                                              const float* __restrict__ msr,
                                              const float* __restrict__ sarr,
                                              const float* __restrict__ bias,
                                              float* __restrict__ neg) {
    __shared__ float Zs[16][68], Ms[16][68], Ss[16][68];  // +4 pad
    int tid = threadIdx.x;
    int tx = tid & 15, ty = tid >> 4;
    int x0 = blockIdx.x * 64, t0 = blockIdx.y * 64, b = blockIdx.z;
    const float* zb = z    + (size_t)b * CC * TYY;
    const float* mb = msr  + (size_t)b * CC * TXX;
    const float* sb = sarr + (size_t)b * CC * TXX;
    int lr = tid >> 4, lc = (tid & 15) * 4;
    float acc[4][4] = {};
    for (int k0 = 0; k0 < CC; k0 += 16) {
        float4 zv = *(const float4*)(zb + (size_t)(k0 + lr) * TYY + t0 + lc);
        float4 mv = *(const float4*)(mb + (size_t)(k0 + lr) * TXX + x0 + lc);
        float4 sv = *(const float4*)(sb + (size_t)(k0 + lr) * TXX + x0 + lc);
        __syncthreads();
        *(float4*)&Zs[lr][lc] = zv;
        *(float4*)&Ms[lr][lc] = mv;
        *(float4*)&Ss[lr][lc] = sv;
        __syncthreads();
#pragma unroll
        for (int k = 0; k < 16; ++k) {
            float4 a4  = *(const float4*)&Zs[k][ty * 4];
            float4 bm4 = *(const float4*)&Ms[k][tx * 4];
            float4 bs4 = *(const float4*)&Ss[k][tx * 4];
            float av[4]  = {a4.x, a4.y, a4.z, a4.w};
            float bmv[4] = {bm4.x, bm4.y, bm4.z, bm4.w};
            float bsv[4] = {bs4.x, bs4.y, bs4.z, bs4.w};
#pragma unroll
            for (int i2 = 0; i2 < 4; ++i2) {
                float a2 = -0.5f * av[i2] * av[i2];
#pragma unroll
                for (int j = 0; j < 4; ++j)
                    acc[i2][j] += av[i2] * bmv[j] + a2 * bsv[j];
            }
        }
    }
    float4 b4 = *(const float4*)(bias + b * TXX + x0 + tx * 4);
    float bv[4] = {b4.x, b4.y, b4.z, b4.w};
#pragma unroll
    for (int i2 = 0; i2 < 4; ++i2) {
        int t = t0 + ty * 4 + i2;
        float4 o;
        o.x = acc[i2][0] + bv[0]; o.y = acc[i2][1] + bv[1];
        o.z = acc[i2][2] + bv[2]; o.w = acc[i2][3] + bv[3];
        *(float4*)(neg + ((size_t)b * TYY + t) * TXX + x0 + tx * 4) = o;
    }
}

// MAS forward pass v3: phase-locked barrier pipeline (no LDS-counter polls).
// R11/R12 post-mortem: DP work is ~80 cyc/row but measured 352 — the
// LDS-counter polling fabric (feed_done/bnd_cnt/consB_cnt, ~120+ cyc
// volatile-LDS round-trips, 4+ hops per group, s_sleep wake lag) is the
// cost, and R8/R9 showed trimming individual fences doesn't move it.
// R13: 258 phase barriers synchronize all 6 waves. Phase p:
//   feeders (waves 2-5, wave w owns rows 2w,2w+1): ds_write group p+1 from
//     registers loaded at phase p-2 (vmcnt wait lands naturally at the
//     ds_write via the per-register scoreboard; ~2 phases ≈ 1400 cyc > 900
//     HBM latency), then issue loads for group p+3 (3 rotating reg buffers).
//   wave A: DP on group p (x<256), publishes v[255] per row to bnd[32] ring.
//   wave B: DP on group p-1 (x>=256), reads bnd (barrier-separated, no poll).
// Barriers are RAW s_barrier + lgkmcnt(0) only — NO vmcnt drain, so feeder
// prefetch stays in flight across barriers (avoids the m97 drain trap).
// DP row body identical to R11 (validated absmax 0.0): DPP wave_shr
// boundary, dir bits 4/lane + DPP lane-pairing, 4 rows/dword, x==y folded.
#define PHASE_BARRIER()                                          \
    do {                                                         \
        asm volatile("s_waitcnt lgkmcnt(0)" ::: "memory");       \
        __builtin_amdgcn_s_barrier();                            \
        asm volatile("" ::: "memory");                           \
    } while (0)

#define FEED_PHASE(P, WBUF, LBUF)                                \
    do {                                                         \
        int p_ = (P);                                            \
        if (p_ + 1 < NG) {                                       \
            float4* lb = (float4*)(ring + (size_t)((p_ + 1) & 3) * 4096); \
            lb[r0 * 128 + lane]      = WBUF[0];                  \
            lb[r0 * 128 + 64 + lane] = WBUF[1];                  \
            lb[r1 * 128 + lane]      = WBUF[2];                  \
            lb[r1 * 128 + 64 + lane] = WBUF[3];                  \
        }                                                        \
        if (p_ + 3 < NG) {                                       \
            const float4* g4 = nc4 + (size_t)(p_ + 3) * 1024;    \
            LBUF[0] = g4[r0 * 128 + lane];                       \
            LBUF[1] = g4[r0 * 128 + 64 + lane];                  \
            LBUF[2] = g4[r1 * 128 + lane];                       \
            LBUF[3] = g4[r1 * 128 + 64 + lane];                  \
        }                                                        \
        PHASE_BARRIER();                                         \
    } while (0)

__global__ __launch_bounds__(384, 1) void k_fwd(const float* __restrict__ neg,
                                                const int* __restrict__ lens,
                                                uint32_t* __restrict__ dirs) {
    __shared__ __align__(16) float ring[4 * 4096];  // 4 slots x 8 rows x 512 f
    __shared__ float bnd[32];                       // A's v[255] ring

    int b = blockIdx.x, tid = threadIdx.x;
    int wave = tid >> 6, lane = tid & 63;
    const float* nc = neg + (size_t)b * TYY * TXX;
    uint32_t* db32 = dirs + (size_t)b * (TYY / 4) * 64;
    (void)lens;

    if (wave >= 2) {
        // ---- feeders: wave w owns rows 2w, 2w+1 of every group ----
        int w = wave - 2;
        int r0 = 2 * w, r1 = 2 * w + 1;
        const float4* nc4 = (const float4*)nc;
        float4 bufA[4], bufB[4], bufC[4];
        {   // prologue: load groups 0,1,2; stage group 0 into slot 0
            const float4* g0 = nc4;
            const float4* g1 = nc4 + 1024;
            const float4* g2 = nc4 + 2048;
            bufA[0] = g0[r0 * 128 + lane]; bufA[1] = g0[r0 * 128 + 64 + lane];
            bufA[2] = g0[r1 * 128 + lane]; bufA[3] = g0[r1 * 128 + 64 + lane];
            bufB[0] = g1[r0 * 128 + lane]; bufB[1] = g1[r0 * 128 + 64 + lane];
            bufB[2] = g1[r1 * 128 + lane]; bufB[3] = g1[r1 * 128 + 64 + lane];
            bufC[0] = g2[r0 * 128 + lane]; bufC[1] = g2[r0 * 128 + 64 + lane];
            bufC[2] = g2[r1 * 128 + lane]; bufC[3] = g2[r1 * 128 + 64 + lane];
            float4* lb = (float4*)ring;
            lb[r0 * 128 + lane]      = bufA[0];
            lb[r0 * 128 + 64 + lane] = bufA[1];
            lb[r1 * 128 + lane]      = bufA[2];
            lb[r1 * 128 + 64 + lane] = bufA[3];
        }
        PHASE_BARRIER();
        // phase p: write group p+1 from buf[(p+1)%3], load group p+3 into
        // buf[p%3]. Unrolled x3 so buffer indices are static.
        for (int p = 0; p <= NG; p += 3) {
            FEED_PHASE(p, bufB, bufA);
            if (p + 1 <= NG) FEED_PHASE(p + 1, bufC, bufB);
            if (p + 2 <= NG) FEED_PHASE(p + 2, bufA, bufC);
        }
        return;
    }

    // ---- DP waves: wave 0 = A (x 0..255) on group p; wave 1 = B (x 256..
    // 511) on group p-1 ----
    bool isA = (wave == 0);
    int xbase = isA ? 0 : 256;
    float v[4];
#pragma unroll
    for (int j = 0; j < 4; ++j) v[j] = NEG_INF;
    uint32_t acc = 0;
    PHASE_BARRIER();   // matches feeder prologue barrier
    for (int p = 0; p <= NG; ++p) {
        int g = isA ? p : p - 1;
        if (g >= 0 && g < NG) {
            float bn[8];
            if (!isA) {
#pragma unroll
                for (int k = 0; k < 8; ++k) bn[k] = bnd[(8 * g - 1 + k) & 31];
            }
            const float4* lb = (const float4*)(ring + (size_t)(g & 3) * 4096)
                               + (isA ? 0 : 64) + lane;
            float4 c_cur = lb[0], c_nxt = lb[128];
#pragma unroll
            for (int r = 0; r < 8; ++r) {
                float4 cpf;
                if (r < 6) cpf = lb[(r + 2) * 128];
                int y = 8 * g + r;
                unsigned d = 0;
                if (y == 0) {
                    if (isA && lane == 0) v[0] = c_cur.x;  // only x==0 scored
                } else {
                    float sc[4] = {c_cur.x, c_cur.y, c_cur.z, c_cur.w};
                    float pl = __int_as_float(__builtin_amdgcn_update_dpp(
                        0, __float_as_int(v[3]), 0x138, 0xF, 0xF, false));
                    if (lane == 0) pl = isA ? NEG_INF : bn[r];
                    float nv[4];
#pragma unroll
                    for (int jj = 0; jj < 4; ++jj) {
                        float diag = (jj == 0) ? pl : v[jj - 1];
                        if (diag > v[jj]) d |= (1u << jj);
                        nv[jj] = sc[jj] + fmaxf(v[jj], diag);
                    }
#pragma unroll
                    for (int jj = 0; jj < 4; ++jj) v[jj] = nv[jj];
                }
                unsigned t_ = (unsigned)(y - (xbase + 4 * lane));
                if (t_ < 4u) d |= (1u << t_);            // fold x==y
                unsigned dl = (unsigned)__builtin_amdgcn_update_dpp(
                    0, (int)d, 0x138, 0xF, 0xF, false);
                unsigned byteval = (d << 4) | dl;
                acc |= byteval << ((r & 3) * 8);
                if ((r & 3) == 3) {
                    if (lane & 1)
                        db32[(y >> 2) * 64 + (isA ? 0 : 32) + (lane >> 1)] = acc;
                    acc = 0;
                }
                if (isA && lane == 63) bnd[y & 31] = v[3];
                c_cur = c_nxt; c_nxt = cpf;
            }
        }
        PHASE_BARRIER();
    }
}

// MAS backtrack: 32-row slabs; lane j holds a 64-bit window of row y0-j's
// bits; move = (idx!=0) & bit (x==y folded in fwd).
__global__ __launch_bounds__(64, 1) void k_bwd(const int* __restrict__ lens,
                                               const uint32_t* __restrict__ dirs,
                                               int* __restrict__ idx_map) {
    int b = blockIdx.x, lane = threadIdx.x;
    const uint32_t* db32 = dirs + (size_t)b * (TYY / 4) * 64;
    int tlen = lens[b], slen = lens[8 + b];

    int idx = tlen - 1;
    int y0 = slen - 1;
    while (y0 >= 0) {
        int nsteps = (y0 + 1 < 32) ? y0 + 1 : 32;
        int y = y0 - lane;
        int yy = (y < 0) ? 0 : y;
        int w0 = (idx >> 5) - 1;
        if (w0 < 0) w0 = 0;
        if (w0 > 14) w0 = 14;
        int qrow = (yy >> 2) * 64;
        int byteoff = (yy & 3) * 8;
        uint32_t lo = 0, hi = 0;
        if (lane < 32) {
#pragma unroll
            for (int k = 0; k < 4; ++k)
                lo |= ((db32[qrow + 4 * w0 + k] >> byteoff) & 0xffu) << (8 * k);
#pragma unroll
            for (int k = 0; k < 4; ++k)
                hi |= ((db32[qrow + 4 * w0 + 4 + k] >> byteoff) & 0xffu) << (8 * k);
        }
        int base = w0 << 5;
        int cap = 0;
#pragma unroll
        for (int j = 0; j < 32; ++j) {
            if (lane == j) cap = idx;
            uint32_t l = (uint32_t)__builtin_amdgcn_readlane((int)lo, j);
            uint32_t h = (uint32_t)__builtin_amdgcn_readlane((int)hi, j);
            int bp = idx - base;              // 0..63
            uint32_t word = (bp & 32) ? h : l;
            int bit = (int)((word >> (bp & 31)) & 1u);
            int move = (int)(idx != 0) & bit;
            idx -= move;
        }
        if (lane < nsteps) idx_map[b * TYY + (y0 - lane)] = cap;
        y0 -= 32;
    }
}

// Scatter path one-hots + duration histogram from idx_map.
__global__ void k_scatter(const int* __restrict__ lens, const int* __restrict__ idx_map,
                          float* __restrict__ out) {
    int i = blockIdx.x * blockDim.x + threadIdx.x;  // B*Ty threads
    int b = i >> 11, y = i & (TYY - 1);
    if (y < lens[8 + b]) {
        int x = idx_map[i];
        out[(size_t)i * TXX + x] = 1.0f;
        atomicAdd(&out[O4 + b * TXX + x], 1.0f);
    }
}

// Gather m_p/logs_p onto spec frames via idx_map; fused KL partial sums.
__global__ __launch_bounds__(256) void k_gather(const float* __restrict__ z_p,
                                                const float* __restrict__ m_p,
                                                const float* __restrict__ logs_p,
                                                const float* __restrict__ logs_q,
                                                const int* __restrict__ lens,
                                                const int* __restrict__ idx_map,
                                                float* __restrict__ out,
                                                float* __restrict__ partials) {
    const int S = BB * CC * TYY / 4;
    int base = blockIdx.x * 256 + threadIdx.x;
    float klsum = 0.f;
#pragma unroll
    for (int r = 0; r < 4; ++r) {
        int i = base + r * S;
        int t = i & (TYY - 1);
        int bc = i >> 11;
        int b = bc / CC;
        float ma = 0.f, la = 0.f;
        if (t < lens[8 + b]) {
            int x = idx_map[b * TYY + t];
            size_t off = (size_t)bc * TXX + x;
            ma = m_p[off];
            la = logs_p[off];
            float zv = z_p[i], lq = logs_q[i];
            float dz = zv - ma;
            klsum += la - lq - 0.5f + 0.5f * dz * dz * expf(-2.0f * la);
        }
        out[O1 + i] = ma;
        out[O2 + i] = la;
    }
    for (int o = 32; o > 0; o >>= 1) klsum += __shfl_down(klsum, o);
    __shared__ float red[4];
    if ((threadIdx.x & 63) == 0) red[threadIdx.x >> 6] = klsum;
    __syncthreads();
    if (threadIdx.x == 0) partials[blockIdx.x] = red[0] + red[1] + red[2] + red[3];
}

__global__ void k_final(const float* __restrict__ partials, const int* __restrict__ lens,
                        float* __restrict__ out) {
    float s = 0.f;
    for (int i = threadIdx.x; i < 3072; i += 256) s += partials[i];
    for (int o = 32; o > 0; o >>= 1) s += __shfl_down(s, o);
    __shared__ float red[4];
    if ((threadIdx.x & 63) == 0) red[threadIdx.x >> 6] = s;
    __syncthreads();
    if (threadIdx.x == 0) {
        float tot = 0.f;
        for (int b = 0; b < 8; ++b) tot += (float)lens[8 + b];
        out[O3] = (red[0] + red[1] + red[2] + red[3]) / tot;
    }
}

extern "C" void kernel_launch(void* const* d_in, const int* in_sizes, int n_in,
                              void* d_out, int out_size, void* d_ws, size_t ws_size,
                              hipStream_t stream) {
    const float* z_p    = (const float*)d_in[0];
    const float* m_p    = (const float*)d_in[1];
    const float* logs_p = (const float*)d_in[2];
    const float* logs_q = (const float*)d_in[3];
    const float* tmask  = (const float*)d_in[4];
    const float* smask  = (const float*)d_in[5];
    float* out = (float*)d_out;
    char* ws = (char*)d_ws;

    float*    neg      = (float*)(ws + WS_NEG);
    float*    sarr     = (float*)(ws + WS_S);
    float*    msr      = (float*)(ws + WS_MSR);
    float*    bias     = (float*)(ws + WS_BIAS);
    uint32_t* dirs     = (uint32_t*)(ws + WS_DIRS);
    int*      idx_map  = (int*)(ws + WS_IDX);
    int*      lens     = (int*)(ws + WS_LENS);
    float*    partials = (float*)(ws + WS_PART);

    hipLaunchKernelGGL(k_zero,    dim3(2048),      dim3(256), 0, stream, out);
    hipLaunchKernelGGL(k_prep,    dim3(3072),      dim3(256), 0, stream, logs_p, m_p, sarr, msr);
    hipLaunchKernelGGL(k_bias,    dim3(16),        dim3(256), 0, stream, logs_p, m_p, msr, bias);
    hipLaunchKernelGGL(k_len,     dim3(8),         dim3(256), 0, stream, tmask, smask, lens);
    hipLaunchKernelGGL(k_gemm,    dim3(8, 32, 8),  dim3(256), 0, stream, z_p, msr, sarr, bias, neg);
    hipLaunchKernelGGL(k_fwd,     dim3(8),         dim3(384), 0, stream, neg, lens, dirs);
    hipLaunchKernelGGL(k_bwd,     dim3(8),         dim3(64),  0, stream, lens, dirs, idx_map);
    hipLaunchKernelGGL(k_scatter, dim3(64),        dim3(256), 0, stream, lens, idx_map, out);
    hipLaunchKernelGGL(k_gather,  dim3(3072),      dim3(256), 0, stream, z_p, m_p, logs_p, logs_q,
                       lens, idx_map, out, partials);
    hipLaunchKernelGGL(k_final,   dim3(1),         dim3(256), 0, stream, partials, lens, out);
}

// Round 14
// 655.275 us; speedup vs baseline: 1.0615x; 1.0286x over previous
//
#include <hip/hip_runtime.h>
#include <cstdint>
#include <cstddef>

// Problem shape (fixed by the reference): B=8, C=192, Tx=512, Ty=2048.
#define BB 8
#define CC 192
#define TXX 512
#define TYY 2048
#define NG_MAX (TYY / 8)   // 256 groups of 8 rows

#define NEG_INF (-1e9f)
#define HALF_LOG_2PI 0.9189385332046727f  // 0.5*log(2*pi)

// ---- output layout (floats, concatenated in return order) ----
#define O1 8388608
#define O2 11534336
#define O3 14680064
#define O4 14680065

// ---- workspace layout (bytes) ----
#define WS_NEG   0           // neg_cent fp32 [B,Ty,Tx]           33,554,432 B
#define WS_S     33554432    // s_p_sq_r [B,C,Tx]                  3,145,728 B
#define WS_MSR   36700160    // m_p * s  [B,C,Tx]                  3,145,728 B
#define WS_BIAS  39845888    // nc1+nc4  [B,Tx]                       16,384 B
#define WS_DIRS  39862272    // dir bits [B,Ty/4,64] dwords        1,048,576 B
#define WS_IDX   40910848    // idx_map  [B,Ty] int                   65,536 B
#define WS_LENS  40976384    // int text_len[8], spec_len[8]             64 B
#define WS_PART  40976448    // kl partials [3072] float              12,288 B

// ---------------------------------------------------------------------------
__global__ void k_zero(float* __restrict__ out) {
    int64_t i = (int64_t)blockIdx.x * blockDim.x + threadIdx.x;
    const int64_t n4 = (int64_t)BB * TYY * TXX / 4;
    float4 z4 = make_float4(0.f, 0.f, 0.f, 0.f);
    float4* p4 = (float4*)out;
    for (int64_t k = i; k < n4; k += (int64_t)gridDim.x * blockDim.x) p4[k] = z4;
    if (i < BB * TXX) out[O4 + i] = 0.0f;
}

__global__ void k_prep(const float* __restrict__ logs_p, const float* __restrict__ m_p,
                       float* __restrict__ s, float* __restrict__ msr) {
    int i = blockIdx.x * blockDim.x + threadIdx.x;
    float lp = logs_p[i], m = m_p[i];
    float sv = expf(-2.0f * lp);
    s[i] = sv;
    msr[i] = m * sv;
}

__global__ void k_bias(const float* __restrict__ logs_p, const float* __restrict__ m_p,
                       const float* __restrict__ msr, float* __restrict__ bias) {
    int i = blockIdx.x * blockDim.x + threadIdx.x;  // B*Tx = 4096 threads
    int b = i >> 9, x = i & (TXX - 1);
    size_t base = (size_t)b * CC * TXX + x;
    const float* lpb = logs_p + base;
    const float* mb  = m_p + base;
    const float* msb = msr + base;
    float acc = 0.f;
#pragma unroll 8
    for (int c = 0; c < CC; ++c)
        acc += -HALF_LOG_2PI - lpb[(size_t)c * TXX] - 0.5f * mb[(size_t)c * TXX] * msb[(size_t)c * TXX];
    bias[i] = acc;
}

__global__ void k_len(const float* __restrict__ tmask, const float* __restrict__ smask,
                      int* __restrict__ lens) {
    __shared__ float red[256];
    int b = blockIdx.x, tid = threadIdx.x;
    float ts = 0.f;
    for (int i = tid; i < TXX; i += 256) ts += tmask[b * TXX + i];
    red[tid] = ts; __syncthreads();
    for (int s = 128; s > 0; s >>= 1) { if (tid < s) red[tid] += red[tid + s]; __syncthreads(); }
    if (tid == 0) lens[b] = (int)(red[0] + 0.5f);
    __syncthreads();
    float ss = 0.f;
    for (int i = tid; i < TYY; i += 256) ss += smask[b * TYY + i];
    red[tid] = ss; __syncthreads();
    for (int s = 128; s > 0; s >>= 1) { if (tid < s) red[tid] += red[tid + s]; __syncthreads(); }
    if (tid == 0) lens[8 + b] = (int)(red[0] + 0.5f);
}

// neg_cent GEMM (R11 v1 tile: 64x64, BK=16, 8 blocks/CU).
// R14: blocks whose tile lies fully in the masked region (x0 >= text_len or
// t0 >= spec_len) exit before any work/barrier (condition is block-uniform).
// Safety: k_fwd only consumes rows y < 8*ceil(slen/8) (covered: their tiles
// have t0 < slen) and columns x >= tlen never influence x < tlen in the DP
// (left-to-right recurrence) nor the backtrack (idx starts at tlen-1).
// Poison floats there (0xAA.. = -3e-13, not NaN) are harmless.
__global__ __launch_bounds__(256) void k_gemm(const float* __restrict__ z,
                                              const float* __restrict__ msr,
                                              const float* __restrict__ sarr,
                                              const float* __restrict__ bias,
                                              const int* __restrict__ lens,
                                              float* __restrict__ neg) {
    int x0 = blockIdx.x * 64, t0 = blockIdx.y * 64, b = blockIdx.z;
    if (x0 >= lens[b] || t0 >= lens[8 + b]) return;   // masked tile

    __shared__ float Zs[16][68], Ms[16][68], Ss[16][68];  // +4 pad
    int tid = threadIdx.x;
    int tx = tid & 15, ty = tid >> 4;
    const float* zb = z    + (size_t)b * CC * TYY;
    const float* mb = msr  + (size_t)b * CC * TXX;
    const float* sb = sarr + (size_t)b * CC * TXX;
    int lr = tid >> 4, lc = (tid & 15) * 4;
    float acc[4][4] = {};
    for (int k0 = 0; k0 < CC; k0 += 16) {
        float4 zv = *(const float4*)(zb + (size_t)(k0 + lr) * TYY + t0 + lc);
        float4 mv = *(const float4*)(mb + (size_t)(k0 + lr) * TXX + x0 + lc);
        float4 sv = *(const float4*)(sb + (size_t)(k0 + lr) * TXX + x0 + lc);
        __syncthreads();
        *(float4*)&Zs[lr][lc] = zv;
        *(float4*)&Ms[lr][lc] = mv;
        *(float4*)&Ss[lr][lc] = sv;
        __syncthreads();
#pragma unroll
        for (int k = 0; k < 16; ++k) {
            float4 a4  = *(const float4*)&Zs[k][ty * 4];
            float4 bm4 = *(const float4*)&Ms[k][tx * 4];
            float4 bs4 = *(const float4*)&Ss[k][tx * 4];
            float av[4]  = {a4.x, a4.y, a4.z, a4.w};
            float bmv[4] = {bm4.x, bm4.y, bm4.z, bm4.w};
            float bsv[4] = {bs4.x, bs4.y, bs4.z, bs4.w};
#pragma unroll
            for (int i2 = 0; i2 < 4; ++i2) {
                float a2 = -0.5f * av[i2] * av[i2];
#pragma unroll
                for (int j = 0; j < 4; ++j)
                    acc[i2][j] += av[i2] * bmv[j] + a2 * bsv[j];
            }
        }
    }
    float4 b4 = *(const float4*)(bias + b * TXX + x0 + tx * 4);
    float bv[4] = {b4.x, b4.y, b4.z, b4.w};
#pragma unroll
    for (int i2 = 0; i2 < 4; ++i2) {
        int t = t0 + ty * 4 + i2;
        float4 o;
        o.x = acc[i2][0] + bv[0]; o.y = acc[i2][1] + bv[1];
        o.z = acc[i2][2] + bv[2]; o.w = acc[i2][3] + bv[3];
        *(float4*)(neg + ((size_t)b * TYY + t) * TXX + x0 + tx * 4) = o;
    }
}

// MAS forward pass v3 (R13 phase-locked barrier pipeline), R14: loop only
// ng = ceil(spec_len/8) groups (rows >= slen are never read by backtrack).
// Feeder and DP sides both execute exactly ng+1 phase barriers + prologue.
#define PHASE_BARRIER()                                          \
    do {                                                         \
        asm volatile("s_waitcnt lgkmcnt(0)" ::: "memory");       \
        __builtin_amdgcn_s_barrier();                            \
        asm volatile("" ::: "memory");                           \
    } while (0)

#define FEED_PHASE(P, WBUF, LBUF)                                \
    do {                                                         \
        int p_ = (P);                                            \
        if (p_ + 1 < ng) {                                       \
            float4* lb = (float4*)(ring + (size_t)((p_ + 1) & 3) * 4096); \
            lb[r0 * 128 + lane]      = WBUF[0];                  \
            lb[r0 * 128 + 64 + lane] = WBUF[1];                  \
            lb[r1 * 128 + lane]      = WBUF[2];                  \
            lb[r1 * 128 + 64 + lane] = WBUF[3];                  \
        }                                                        \
        if (p_ + 3 < ng) {                                       \
            const float4* g4 = nc4 + (size_t)(p_ + 3) * 1024;    \
            LBUF[0] = g4[r0 * 128 + lane];                       \
            LBUF[1] = g4[r0 * 128 + 64 + lane];                  \
            LBUF[2] = g4[r1 * 128 + lane];                       \
            LBUF[3] = g4[r1 * 128 + 64 + lane];                  \
        }                                                        \
        PHASE_BARRIER();                                         \
    } while (0)

__global__ __launch_bounds__(384, 1) void k_fwd(const float* __restrict__ neg,
                                                const int* __restrict__ lens,
                                                uint32_t* __restrict__ dirs) {
    __shared__ __align__(16) float ring[4 * 4096];  // 4 slots x 8 rows x 512 f
    __shared__ float bnd[32];                       // A's v[255] ring

    int b = blockIdx.x, tid = threadIdx.x;
    int wave = tid >> 6, lane = tid & 63;
    const float* nc = neg + (size_t)b * TYY * TXX;
    uint32_t* db32 = dirs + (size_t)b * (TYY / 4) * 64;
    int slen = lens[8 + b];
    int ng = (slen + 7) >> 3;    // 192..256 (slen >= 1536)

    if (wave >= 2) {
        // ---- feeders: wave w owns rows 2w, 2w+1 of every group ----
        int w = wave - 2;
        int r0 = 2 * w, r1 = 2 * w + 1;
        const float4* nc4 = (const float4*)nc;
        float4 bufA[4], bufB[4], bufC[4];
        {   // prologue: load groups 0,1,2; stage group 0 into slot 0
            const float4* g0 = nc4;
            const float4* g1 = nc4 + 1024;
            const float4* g2 = nc4 + 2048;
            bufA[0] = g0[r0 * 128 + lane]; bufA[1] = g0[r0 * 128 + 64 + lane];
            bufA[2] = g0[r1 * 128 + lane]; bufA[3] = g0[r1 * 128 + 64 + lane];
            bufB[0] = g1[r0 * 128 + lane]; bufB[1] = g1[r0 * 128 + 64 + lane];
            bufB[2] = g1[r1 * 128 + lane]; bufB[3] = g1[r1 * 128 + 64 + lane];
            bufC[0] = g2[r0 * 128 + lane]; bufC[1] = g2[r0 * 128 + 64 + lane];
            bufC[2] = g2[r1 * 128 + lane]; bufC[3] = g2[r1 * 128 + 64 + lane];
            float4* lb = (float4*)ring;
            lb[r0 * 128 + lane]      = bufA[0];
            lb[r0 * 128 + 64 + lane] = bufA[1];
            lb[r1 * 128 + lane]      = bufA[2];
            lb[r1 * 128 + 64 + lane] = bufA[3];
        }
        PHASE_BARRIER();
        for (int p = 0; p <= ng; p += 3) {
            FEED_PHASE(p, bufB, bufA);
            if (p + 1 <= ng) FEED_PHASE(p + 1, bufC, bufB);
            if (p + 2 <= ng) FEED_PHASE(p + 2, bufA, bufC);
        }
        return;
    }

    // ---- DP waves: wave 0 = A (x 0..255) on group p; wave 1 = B on p-1 ----
    bool isA = (wave == 0);
    int xbase = isA ? 0 : 256;
    float v[4];
#pragma unroll
    for (int j = 0; j < 4; ++j) v[j] = NEG_INF;
    uint32_t acc = 0;
    PHASE_BARRIER();   // matches feeder prologue barrier
    for (int p = 0; p <= ng; ++p) {
        int g = isA ? p : p - 1;
        if (g >= 0 && g < ng) {
            float bn[8];
            if (!isA) {
#pragma unroll
                for (int k = 0; k < 8; ++k) bn[k] = bnd[(8 * g - 1 + k) & 31];
            }
            const float4* lb = (const float4*)(ring + (size_t)(g & 3) * 4096)
                               + (isA ? 0 : 64) + lane;
            float4 c_cur = lb[0], c_nxt = lb[128];
#pragma unroll
            for (int r = 0; r < 8; ++r) {
                float4 cpf;
                if (r < 6) cpf = lb[(r + 2) * 128];
                int y = 8 * g + r;
                unsigned d = 0;
                if (y == 0) {
                    if (isA && lane == 0) v[0] = c_cur.x;  // only x==0 scored
                } else {
                    float sc[4] = {c_cur.x, c_cur.y, c_cur.z, c_cur.w};
                    float pl = __int_as_float(__builtin_amdgcn_update_dpp(
                        0, __float_as_int(v[3]), 0x138, 0xF, 0xF, false));
                    if (lane == 0) pl = isA ? NEG_INF : bn[r];
                    float nv[4];
#pragma unroll
                    for (int jj = 0; jj < 4; ++jj) {
                        float diag = (jj == 0) ? pl : v[jj - 1];
                        if (diag > v[jj]) d |= (1u << jj);
                        nv[jj] = sc[jj] + fmaxf(v[jj], diag);
                    }
#pragma unroll
                    for (int jj = 0; jj < 4; ++jj) v[jj] = nv[jj];
                }
                unsigned t_ = (unsigned)(y - (xbase + 4 * lane));
                if (t_ < 4u) d |= (1u << t_);            // fold x==y
                unsigned dl = (unsigned)__builtin_amdgcn_update_dpp(
                    0, (int)d, 0x138, 0xF, 0xF, false);
                unsigned byteval = (d << 4) | dl;
                acc |= byteval << ((r & 3) * 8);
                if ((r & 3) == 3) {
                    if (lane & 1)
                        db32[(y >> 2) * 64 + (isA ? 0 : 32) + (lane >> 1)] = acc;
                    acc = 0;
                }
                if (isA && lane == 63) bnd[y & 31] = v[3];
                c_cur = c_nxt; c_nxt = cpf;
            }
        }
        PHASE_BARRIER();
    }
}

// MAS backtrack: 32-row slabs; lane j holds a 64-bit window of row y0-j's
// bits; move = (idx!=0) & bit (x==y folded in fwd).
__global__ __launch_bounds__(64, 1) void k_bwd(const int* __restrict__ lens,
                                               const uint32_t* __restrict__ dirs,
                                               int* __restrict__ idx_map) {
    int b = blockIdx.x, lane = threadIdx.x;
    const uint32_t* db32 = dirs + (size_t)b * (TYY / 4) * 64;
    int tlen = lens[b], slen = lens[8 + b];

    int idx = tlen - 1;
    int y0 = slen - 1;
    while (y0 >= 0) {
        int nsteps = (y0 + 1 < 32) ? y0 + 1 : 32;
        int y = y0 - lane;
        int yy = (y < 0) ? 0 : y;
        int w0 = (idx >> 5) - 1;
        if (w0 < 0) w0 = 0;
        if (w0 > 14) w0 = 14;
        int qrow = (yy >> 2) * 64;
        int byteoff = (yy & 3) * 8;
        uint32_t lo = 0, hi = 0;
        if (lane < 32) {
#pragma unroll
            for (int k = 0; k < 4; ++k)
                lo |= ((db32[qrow + 4 * w0 + k] >> byteoff) & 0xffu) << (8 * k);
#pragma unroll
            for (int k = 0; k < 4; ++k)
                hi |= ((db32[qrow + 4 * w0 + 4 + k] >> byteoff) & 0xffu) << (8 * k);
        }
        int base = w0 << 5;
        int cap = 0;
#pragma unroll
        for (int j = 0; j < 32; ++j) {
            if (lane == j) cap = idx;
            uint32_t l = (uint32_t)__builtin_amdgcn_readlane((int)lo, j);
            uint32_t h = (uint32_t)__builtin_amdgcn_readlane((int)hi, j);
            int bp = idx - base;              // 0..63
            uint32_t word = (bp & 32) ? h : l;
            int bit = (int)((word >> (bp & 31)) & 1u);
            int move = (int)(idx != 0) & bit;
            idx -= move;
        }
        if (lane < nsteps) idx_map[b * TYY + (y0 - lane)] = cap;
        y0 -= 32;
    }
}

// Scatter path one-hots + duration histogram from idx_map.
__global__ void k_scatter(const int* __restrict__ lens, const int* __restrict__ idx_map,
                          float* __restrict__ out) {
    int i = blockIdx.x * blockDim.x + threadIdx.x;  // B*Ty threads
    int b = i >> 11, y = i & (TYY - 1);
    if (y < lens[8 + b]) {
        int x = idx_map[i];
        out[(size_t)i * TXX + x] = 1.0f;
        atomicAdd(&out[O4 + b * TXX + x], 1.0f);
    }
}

// Gather m_p/logs_p onto spec frames via idx_map; fused KL partial sums.
__global__ __launch_bounds__(256) void k_gather(const float* __restrict__ z_p,
                                                const float* __restrict__ m_p,
                                                const float* __restrict__ logs_p,
                                                const float* __restrict__ logs_q,
                                                const int* __restrict__ lens,
                                                const int* __restrict__ idx_map,
                                                float* __restrict__ out,
                                                float* __restrict__ partials) {
    const int S = BB * CC * TYY / 4;
    int base = blockIdx.x * 256 + threadIdx.x;
    float klsum = 0.f;
#pragma unroll
    for (int r = 0; r < 4; ++r) {
        int i = base + r * S;
        int t = i & (TYY - 1);
        int bc = i >> 11;
        int b = bc / CC;
        float ma = 0.f, la = 0.f;
        if (t < lens[8 + b]) {
            int x = idx_map[b * TYY + t];
            size_t off = (size_t)bc * TXX + x;
            ma = m_p[off];
            la = logs_p[off];
            float zv = z_p[i], lq = logs_q[i];
            float dz = zv - ma;
            klsum += la - lq - 0.5f + 0.5f * dz * dz * expf(-2.0f * la);
        }
        out[O1 + i] = ma;
        out[O2 + i] = la;
    }
    for (int o = 32; o > 0; o >>= 1) klsum += __shfl_down(klsum, o);
    __shared__ float red[4];
    if ((threadIdx.x & 63) == 0) red[threadIdx.x >> 6] = klsum;
    __syncthreads();
    if (threadIdx.x == 0) partials[blockIdx.x] = red[0] + red[1] + red[2] + red[3];
}

__global__ void k_final(const float* __restrict__ partials, const int* __restrict__ lens,
                        float* __restrict__ out) {
    float s = 0.f;
    for (int i = threadIdx.x; i < 3072; i += 256) s += partials[i];
    for (int o = 32; o > 0; o >>= 1) s += __shfl_down(s, o);
    __shared__ float red[4];
    if ((threadIdx.x & 63) == 0) red[threadIdx.x >> 6] = s;
    __syncthreads();
    if (threadIdx.x == 0) {
        float tot = 0.f;
        for (int b = 0; b < 8; ++b) tot += (float)lens[8 + b];
        out[O3] = (red[0] + red[1] + red[2] + red[3]) / tot;
    }
}

extern "C" void kernel_launch(void* const* d_in, const int* in_sizes, int n_in,
                              void* d_out, int out_size, void* d_ws, size_t ws_size,
                              hipStream_t stream) {
    const float* z_p    = (const float*)d_in[0];
    const float* m_p    = (const float*)d_in[1];
    const float* logs_p = (const float*)d_in[2];
    const float* logs_q = (const float*)d_in[3];
    const float* tmask  = (const float*)d_in[4];
    const float* smask  = (const float*)d_in[5];
    float* out = (float*)d_out;
    char* ws = (char*)d_ws;

    float*    neg      = (float*)(ws + WS_NEG);
    float*    sarr     = (float*)(ws + WS_S);
    float*    msr      = (float*)(ws + WS_MSR);
    float*    bias     = (float*)(ws + WS_BIAS);
    uint32_t* dirs     = (uint32_t*)(ws + WS_DIRS);
    int*      idx_map  = (int*)(ws + WS_IDX);
    int*      lens     = (int*)(ws + WS_LENS);
    float*    partials = (float*)(ws + WS_PART);

    hipLaunchKernelGGL(k_zero,    dim3(2048),      dim3(256), 0, stream, out);
    hipLaunchKernelGGL(k_prep,    dim3(3072),      dim3(256), 0, stream, logs_p, m_p, sarr, msr);
    hipLaunchKernelGGL(k_bias,    dim3(16),        dim3(256), 0, stream, logs_p, m_p, msr, bias);
    hipLaunchKernelGGL(k_len,     dim3(8),         dim3(256), 0, stream, tmask, smask, lens);
    hipLaunchKernelGGL(k_gemm,    dim3(8, 32, 8),  dim3(256), 0, stream, z_p, msr, sarr, bias, lens, neg);
    hipLaunchKernelGGL(k_fwd,     dim3(8),         dim3(384), 0, stream, neg, lens, dirs);
    hipLaunchKernelGGL(k_bwd,     dim3(8),         dim3(64),  0, stream, lens, dirs, idx_map);
    hipLaunchKernelGGL(k_scatter, dim3(64),        dim3(256), 0, stream, lens, idx_map, out);
    hipLaunchKernelGGL(k_gather,  dim3(3072),      dim3(256), 0, stream, z_p, m_p, logs_p, logs_q,
                       lens, idx_map, out, partials);
    hipLaunchKernelGGL(k_final,   dim3(1),         dim3(256), 0, stream, partials, lens, out);
}